// Round 2
// baseline (352.608 us; speedup 1.0000x reference)
//
#include <hip/hip_runtime.h>
#include <math.h>

#define N_LEVELS 24
#define LV_PER_THREAD 6
#define SPLIT 4
#define CAPACITY 262144u
#define CAP_MASK 0x3FFFFu

struct ScaleArg { float s[N_LEVELS]; };

__global__ __launch_bounds__(256)
void permuto_enc(const float* __restrict__ pos,
                 const float* __restrict__ lattice,
                 const float* __restrict__ rshift,
                 const float* __restrict__ anneal,
                 float* __restrict__ out,
                 ScaleArg sc, int npts)
{
#pragma clang fp contract(off)
    __shared__ float sh_scale[N_LEVELS];
    __shared__ float sh_shift[N_LEVELS][3];
    __shared__ float sh_ann[N_LEVELS];
    const int tid = threadIdx.x;
    if (tid < N_LEVELS) {
        sh_scale[tid] = sc.s[tid];
        sh_shift[tid][0] = rshift[tid * 3 + 0];
        sh_shift[tid][1] = rshift[tid * 3 + 1];
        sh_shift[tid][2] = rshift[tid * 3 + 2];
        sh_ann[tid] = anneal[tid];
    }
    __syncthreads();

    const int gtid = blockIdx.x * 256 + tid;
    const int n = gtid >> 2;          // point index
    const int h = gtid & 3;           // level-group: levels h*6 .. h*6+5
    if (n >= npts) return;

    const float p0 = pos[n * 3 + 0];
    const float p1 = pos[n * 3 + 1];
    const float p2 = pos[n * 3 + 2];

    // f32(INV_STD_DEV / sqrt((i+1)*(i+2))), INV_STD_DEV = 4*sqrt(2/3)
    const float sf0 = 2.3094010767585034f;
    const float sf1 = 1.3333333333333335f;
    const float sf2 = 0.9428090415820634f;

    const float2* __restrict__ tab = (const float2*)lattice;

    float resx[LV_PER_THREAD];
    float resy[LV_PER_THREAD];

    const int l0 = h * LV_PER_THREAD;

#pragma unroll
    for (int i = 0; i < LV_PER_THREAD; ++i) {
        const int l = l0 + i;
        const float scale = sh_scale[l];
        // p/scale + shift  (true IEEE divide, matches np f32 op order)
        const float q0 = p0 / scale + sh_shift[l][0];
        const float q1 = p1 / scale + sh_shift[l][1];
        const float q2 = p2 / scale + sh_shift[l][2];
        const float cf0 = q0 * sf0;
        const float cf1 = q1 * sf1;
        const float cf2 = q2 * sf2;

        // elevated (matches reversed-cumsum order: rc1 = cf2+cf1; rc0 = rc1+cf0)
        const float rc1 = cf2 + cf1;
        const float el0 = rc1 + cf0;
        const float el1 = rc1 - cf0;          // rc1 - 1*cf0
        const float el2 = cf2 - 2.0f * cf1;
        const float el3 = 0.0f - 3.0f * cf2;

        // rem0 = round(el/4)*4  (rintf == np.round, half-to-even; /4 and *4 exact)
        float r0 = rintf(el0 * 0.25f) * 4.0f;
        float r1 = rintf(el1 * 0.25f) * 4.0f;
        float r2 = rintf(el2 * 0.25f) * 4.0f;
        float r3 = rintf(el3 * 0.25f) * 4.0f;

        const float d0 = el0 - r0;
        const float d1 = el1 - r1;
        const float d2 = el2 - r2;
        const float d3 = el3 - r3;

        // rank: for i<j, if d[i]<d[j] rank[i]++ else rank[j]++
        int k0 = 0, k1 = 0, k2 = 0, k3 = 0;
        if (d0 < d1) k0++; else k1++;
        if (d0 < d2) k0++; else k2++;
        if (d0 < d3) k0++; else k3++;
        if (d1 < d2) k1++; else k2++;
        if (d1 < d3) k1++; else k3++;
        if (d2 < d3) k2++; else k3++;

        const int s = (int)rintf((((r0 + r1) + r2) + r3) * 0.25f);
        k0 += s; k1 += s; k2 += s; k3 += s;

        if (k0 < 0) { k0 += 4; r0 += 4.0f; } else if (k0 > 3) { k0 -= 4; r0 -= 4.0f; }
        if (k1 < 0) { k1 += 4; r1 += 4.0f; } else if (k1 > 3) { k1 -= 4; r1 -= 4.0f; }
        if (k2 < 0) { k2 += 4; r2 += 4.0f; } else if (k2 > 3) { k2 -= 4; r2 -= 4.0f; }
        if (k3 < 0) { k3 += 4; r3 += 4.0f; } else if (k3 > 3) { k3 -= 4; r3 -= 4.0f; }

        const float dl0 = (el0 - r0) * 0.25f;
        const float dl1 = (el1 - r1) * 0.25f;
        const float dl2 = (el2 - r2) * 0.25f;
        const float dl3 = (el3 - r3) * 0.25f;

        // g[r] = delta of the coord whose rank == r  (rank is a permutation of 0..3)
        const float g0 = (k0 == 0 ? dl0 : 0.0f) + (k1 == 0 ? dl1 : 0.0f) + (k2 == 0 ? dl2 : 0.0f) + (k3 == 0 ? dl3 : 0.0f);
        const float g1 = (k0 == 1 ? dl0 : 0.0f) + (k1 == 1 ? dl1 : 0.0f) + (k2 == 1 ? dl2 : 0.0f) + (k3 == 1 ? dl3 : 0.0f);
        const float g2 = (k0 == 2 ? dl0 : 0.0f) + (k1 == 2 ? dl1 : 0.0f) + (k2 == 2 ? dl2 : 0.0f) + (k3 == 2 ? dl3 : 0.0f);
        const float g3 = (k0 == 3 ? dl0 : 0.0f) + (k1 == 3 ? dl1 : 0.0f) + (k2 == 3 ? dl2 : 0.0f) + (k3 == 3 ? dl3 : 0.0f);

        // weights: w0 = (g3 + 1) - g0 ; w1 = g2-g3 ; w2 = g1-g2 ; w3 = g0-g1
        const float w0 = g3 + 1.0f - g0;
        const float w1 = g2 - g3;
        const float w2 = g1 - g2;
        const float w3 = g0 - g1;

        const int i0 = (int)r0;
        const int i1 = (int)r1;
        const int i2 = (int)r2;

        float acc0 = 0.0f, acc1 = 0.0f;
        const unsigned lbase = (unsigned)l * CAPACITY;
#pragma unroll
        for (int r = 0; r < 4; ++r) {
            const int key0 = i0 + r - ((k0 > 3 - r) ? 4 : 0);
            const int key1 = i1 + r - ((k1 > 3 - r) ? 4 : 0);
            const int key2 = i2 + r - ((k2 > 3 - r) ? 4 : 0);
            const unsigned hsh = (unsigned)key0 * 2654435761u
                               ^ (unsigned)key1 * 805459861u
                               ^ (unsigned)key2 * 3674653429u;
            const unsigned idx = hsh & CAP_MASK;
            const float2 v = tab[lbase + idx];
            const float w = (r == 0) ? w0 : (r == 1) ? w1 : (r == 2) ? w2 : w3;
            acc0 += w * v.x;
            acc1 += w * v.y;
        }
        const float a = sh_ann[l];
        resx[i] = acc0 * a;
        resy[i] = acc1 * a;
    }

    // dense 48 B store per thread: wave covers 12 KB contiguous, no partial lines
    float4* __restrict__ ov = (float4*)(out + (size_t)n * 48 + (size_t)h * 12);
    ov[0] = make_float4(resx[0], resy[0], resx[1], resy[1]);
    ov[1] = make_float4(resx[2], resy[2], resx[3], resy[3]);
    ov[2] = make_float4(resx[4], resy[4], resx[5], resy[5]);
}

extern "C" void kernel_launch(void* const* d_in, const int* in_sizes, int n_in,
                              void* d_out, int out_size, void* d_ws, size_t ws_size,
                              hipStream_t stream) {
    const float* pos     = (const float*)d_in[0];
    const float* lattice = (const float*)d_in[1];
    const float* rshift  = (const float*)d_in[2];
    const float* anneal  = (const float*)d_in[3];
    float* out = (float*)d_out;
    const int npts = in_sizes[0] / 3;

    // np.geomspace(1.0, 1e-4, 24).astype(f32): 10**(i * (-4/23)), endpoints pinned
    ScaleArg sc;
    for (int i = 0; i < N_LEVELS; ++i)
        sc.s[i] = (float)pow(10.0, (double)i * (-4.0 / 23.0));
    sc.s[0] = 1.0f;
    sc.s[N_LEVELS - 1] = 1e-4f;

    const int threads_total = npts * SPLIT;
    const int blocks = (threads_total + 255) / 256;
    permuto_enc<<<blocks, 256, 0, stream>>>(pos, lattice, rshift, anneal, out, sc, npts);
}

// Round 3
// 244.866 us; speedup vs baseline: 1.4400x; 1.4400x over previous
//
#include <hip/hip_runtime.h>
#include <math.h>

#define N_LEVELS 24
#define CAPACITY 262144u
#define CAP_MASK 0x3FFFFu

struct ScaleArg { float s[N_LEVELS]; };

// Per-(point,level) permutohedral interpolation. Bit-exact vs numpy f32 ref:
// no FMA contraction, IEEE divide, rintf == np.round (half-even).
__device__ __forceinline__ float2 permuto_level(
    float p0, float p1, float p2,
    float scale, float s0, float s1, float s2,
    const float2* __restrict__ tab /* level base */)
{
#pragma clang fp contract(off)
    // f32(INV_STD_DEV / sqrt((i+1)*(i+2))), INV_STD_DEV = 4*sqrt(2/3)
    const float sf0 = 2.3094010767585034f;
    const float sf1 = 1.3333333333333335f;
    const float sf2 = 0.9428090415820634f;

    const float q0 = p0 / scale + s0;
    const float q1 = p1 / scale + s1;
    const float q2 = p2 / scale + s2;
    const float cf0 = q0 * sf0;
    const float cf1 = q1 * sf1;
    const float cf2 = q2 * sf2;

    // elevated (reversed-cumsum order: rc1 = cf2+cf1; el0 = rc1+cf0)
    const float rc1 = cf2 + cf1;
    const float el0 = rc1 + cf0;
    const float el1 = rc1 - cf0;
    const float el2 = cf2 - 2.0f * cf1;
    const float el3 = 0.0f - 3.0f * cf2;

    // rem0 = round(el/4)*4  (exact: /4, *4 are exponent shifts)
    float r0 = rintf(el0 * 0.25f) * 4.0f;
    float r1 = rintf(el1 * 0.25f) * 4.0f;
    float r2 = rintf(el2 * 0.25f) * 4.0f;
    float r3 = rintf(el3 * 0.25f) * 4.0f;

    const float d0 = el0 - r0;
    const float d1 = el1 - r1;
    const float d2 = el2 - r2;
    const float d3 = el3 - r3;

    int k0 = 0, k1 = 0, k2 = 0, k3 = 0;
    if (d0 < d1) k0++; else k1++;
    if (d0 < d2) k0++; else k2++;
    if (d0 < d3) k0++; else k3++;
    if (d1 < d2) k1++; else k2++;
    if (d1 < d3) k1++; else k3++;
    if (d2 < d3) k2++; else k3++;

    const int s = (int)rintf((((r0 + r1) + r2) + r3) * 0.25f);
    k0 += s; k1 += s; k2 += s; k3 += s;

    if (k0 < 0) { k0 += 4; r0 += 4.0f; } else if (k0 > 3) { k0 -= 4; r0 -= 4.0f; }
    if (k1 < 0) { k1 += 4; r1 += 4.0f; } else if (k1 > 3) { k1 -= 4; r1 -= 4.0f; }
    if (k2 < 0) { k2 += 4; r2 += 4.0f; } else if (k2 > 3) { k2 -= 4; r2 -= 4.0f; }
    if (k3 < 0) { k3 += 4; r3 += 4.0f; } else if (k3 > 3) { k3 -= 4; r3 -= 4.0f; }

    const float dl0 = (el0 - r0) * 0.25f;
    const float dl1 = (el1 - r1) * 0.25f;
    const float dl2 = (el2 - r2) * 0.25f;
    const float dl3 = (el3 - r3) * 0.25f;

    // g[r] = delta of the coord whose rank == r
    const float g0 = (k0 == 0 ? dl0 : 0.0f) + (k1 == 0 ? dl1 : 0.0f) + (k2 == 0 ? dl2 : 0.0f) + (k3 == 0 ? dl3 : 0.0f);
    const float g1 = (k0 == 1 ? dl0 : 0.0f) + (k1 == 1 ? dl1 : 0.0f) + (k2 == 1 ? dl2 : 0.0f) + (k3 == 1 ? dl3 : 0.0f);
    const float g2 = (k0 == 2 ? dl0 : 0.0f) + (k1 == 2 ? dl1 : 0.0f) + (k2 == 2 ? dl2 : 0.0f) + (k3 == 2 ? dl3 : 0.0f);
    const float g3 = (k0 == 3 ? dl0 : 0.0f) + (k1 == 3 ? dl1 : 0.0f) + (k2 == 3 ? dl2 : 0.0f) + (k3 == 3 ? dl3 : 0.0f);

    const float w0 = g3 + 1.0f - g0;
    const float w1 = g2 - g3;
    const float w2 = g1 - g2;
    const float w3 = g0 - g1;

    const int i0 = (int)r0;
    const int i1 = (int)r1;
    const int i2 = (int)r2;

    float acc0 = 0.0f, acc1 = 0.0f;
#pragma unroll
    for (int r = 0; r < 4; ++r) {
        const int key0 = i0 + r - ((k0 > 3 - r) ? 4 : 0);
        const int key1 = i1 + r - ((k1 > 3 - r) ? 4 : 0);
        const int key2 = i2 + r - ((k2 > 3 - r) ? 4 : 0);
        const unsigned hsh = (unsigned)key0 * 2654435761u
                           ^ (unsigned)key1 * 805459861u
                           ^ (unsigned)key2 * 3674653429u;
        const float2 v = tab[hsh & CAP_MASK];
        const float w = (r == 0) ? w0 : (r == 1) ? w1 : (r == 2) ? w2 : w3;
        acc0 += w * v.x;
        acc1 += w * v.y;
    }
    return make_float2(acc0, acc1);
}

// Pass 1: level-major gather with XCD affinity. XCD k (= blockIdx&7) only
// touches levels {k, 8+k, 16+k} -> one 2MB table L2-resident at a time,
// each table fetched by exactly one XCD. Dense level-major write to ws.
__global__ __launch_bounds__(256)
void permuto_gather(const float* __restrict__ pos,
                    const float* __restrict__ lattice,
                    const float* __restrict__ rshift,
                    const float* __restrict__ anneal,
                    float2* __restrict__ ws,
                    ScaleArg sc, int npts, int chunksPerLevel)
{
#pragma clang fp contract(off)
    const int i = blockIdx.x;
    const int xcd = i & 7;
    const int j = i >> 3;
    const int phase = j / chunksPerLevel;        // 0..2
    const int chunk = j - phase * chunksPerLevel;
    const int level = phase * 8 + xcd;           // coarse/mid/fine mix per XCD

    const int n = chunk * 256 + threadIdx.x;
    if (n >= npts) return;

    const float scale = sc.s[level];
    const float s0 = rshift[level * 3 + 0];      // wave-uniform -> scalar loads
    const float s1 = rshift[level * 3 + 1];
    const float s2 = rshift[level * 3 + 2];
    const float a  = anneal[level];

    const float p0 = pos[n * 3 + 0];
    const float p1 = pos[n * 3 + 1];
    const float p2 = pos[n * 3 + 2];

    const float2* tab = (const float2*)lattice + (size_t)level * CAPACITY;
    float2 acc = permuto_level(p0, p1, p2, scale, s0, s1, s2, tab);
    ws[(size_t)level * npts + n] = make_float2(acc.x * a, acc.y * a);
}

// Pass 2: (L,N,2) -> (N,L,2). Coalesced strided reads, dense 48B/point writes.
__global__ __launch_bounds__(256)
void permuto_transpose(const float2* __restrict__ ws,
                       float4* __restrict__ out, int npts)
{
    const int n = blockIdx.x * 256 + threadIdx.x;
    if (n >= npts) return;
    float2 v[N_LEVELS];
#pragma unroll
    for (int l = 0; l < N_LEVELS; ++l)
        v[l] = ws[(size_t)l * npts + n];
    float4* o = out + (size_t)n * (N_LEVELS / 2);
#pragma unroll
    for (int k = 0; k < N_LEVELS / 2; ++k)
        o[k] = make_float4(v[2 * k].x, v[2 * k].y, v[2 * k + 1].x, v[2 * k + 1].y);
}

// Fallback (ws too small): R1 monolithic kernel, one thread per point.
__global__ __launch_bounds__(256)
void permuto_mono(const float* __restrict__ pos,
                  const float* __restrict__ lattice,
                  const float* __restrict__ rshift,
                  const float* __restrict__ anneal,
                  float* __restrict__ out,
                  ScaleArg sc, int npts)
{
#pragma clang fp contract(off)
    __shared__ float sh_shift[N_LEVELS][3];
    __shared__ float sh_ann[N_LEVELS];
    const int tid = threadIdx.x;
    if (tid < N_LEVELS) {
        sh_shift[tid][0] = rshift[tid * 3 + 0];
        sh_shift[tid][1] = rshift[tid * 3 + 1];
        sh_shift[tid][2] = rshift[tid * 3 + 2];
        sh_ann[tid] = anneal[tid];
    }
    __syncthreads();

    const int n = blockIdx.x * 256 + tid;
    if (n >= npts) return;
    const float p0 = pos[n * 3 + 0];
    const float p1 = pos[n * 3 + 1];
    const float p2 = pos[n * 3 + 2];
    float2* outv = (float2*)out + (size_t)n * N_LEVELS;
    for (int l = 0; l < N_LEVELS; ++l) {
        const float2* tab = (const float2*)lattice + (size_t)l * CAPACITY;
        float2 acc = permuto_level(p0, p1, p2, sc.s[l],
                                   sh_shift[l][0], sh_shift[l][1], sh_shift[l][2], tab);
        outv[l] = make_float2(acc.x * sh_ann[l], acc.y * sh_ann[l]);
    }
}

extern "C" void kernel_launch(void* const* d_in, const int* in_sizes, int n_in,
                              void* d_out, int out_size, void* d_ws, size_t ws_size,
                              hipStream_t stream) {
    const float* pos     = (const float*)d_in[0];
    const float* lattice = (const float*)d_in[1];
    const float* rshift  = (const float*)d_in[2];
    const float* anneal  = (const float*)d_in[3];
    const int npts = in_sizes[0] / 3;

    // np.geomspace(1.0, 1e-4, 24).astype(f32): 10**(i * (-4/23)), endpoints pinned
    ScaleArg sc;
    for (int i = 0; i < N_LEVELS; ++i)
        sc.s[i] = (float)pow(10.0, (double)i * (-4.0 / 23.0));
    sc.s[0] = 1.0f;
    sc.s[N_LEVELS - 1] = 1e-4f;

    const size_t ws_need = (size_t)N_LEVELS * (size_t)npts * sizeof(float2);
    if (ws_size >= ws_need) {
        const int C = (npts + 255) / 256;          // chunks per level
        const int blocks1 = 8 * 3 * C;             // 24 * C, xcd-swizzled
        permuto_gather<<<blocks1, 256, 0, stream>>>(
            pos, lattice, rshift, anneal, (float2*)d_ws, sc, npts, C);
        const int blocks2 = (npts + 255) / 256;
        permuto_transpose<<<blocks2, 256, 0, stream>>>(
            (const float2*)d_ws, (float4*)d_out, npts);
    } else {
        const int blocks = (npts + 255) / 256;
        permuto_mono<<<blocks, 256, 0, stream>>>(
            pos, lattice, rshift, anneal, (float*)d_out, sc, npts);
    }
}

// Round 4
// 211.059 us; speedup vs baseline: 1.6707x; 1.1602x over previous
//
#include <hip/hip_runtime.h>
#include <math.h>

#define N_LEVELS 24
#define CAPACITY 262144u
#define CAP_MASK 0x3FFFFu

struct ScaleArg { float s[N_LEVELS]; };

// Weights + hash indices for one (point, level). Bit-exact vs numpy f32 ref:
// no FMA contraction, IEEE divide, rintf == np.round (half-even).
struct Prep {
    float w0, w1, w2, w3;
    unsigned i0, i1, i2, i3;
};

__device__ __forceinline__ Prep permuto_prep(
    float p0, float p1, float p2,
    float scale, float s0, float s1, float s2)
{
#pragma clang fp contract(off)
    // f32(INV_STD_DEV / sqrt((i+1)*(i+2))), INV_STD_DEV = 4*sqrt(2/3)
    const float sf0 = 2.3094010767585034f;
    const float sf1 = 1.3333333333333335f;
    const float sf2 = 0.9428090415820634f;

    const float q0 = p0 / scale + s0;
    const float q1 = p1 / scale + s1;
    const float q2 = p2 / scale + s2;
    const float cf0 = q0 * sf0;
    const float cf1 = q1 * sf1;
    const float cf2 = q2 * sf2;

    // elevated (reversed-cumsum order: rc1 = cf2+cf1; el0 = rc1+cf0)
    const float rc1 = cf2 + cf1;
    const float el0 = rc1 + cf0;
    const float el1 = rc1 - cf0;
    const float el2 = cf2 - 2.0f * cf1;
    const float el3 = 0.0f - 3.0f * cf2;

    // rem0 = round(el/4)*4  (exact: /4, *4 are exponent shifts)
    float r0 = rintf(el0 * 0.25f) * 4.0f;
    float r1 = rintf(el1 * 0.25f) * 4.0f;
    float r2 = rintf(el2 * 0.25f) * 4.0f;
    float r3 = rintf(el3 * 0.25f) * 4.0f;

    const float d0 = el0 - r0;
    const float d1 = el1 - r1;
    const float d2 = el2 - r2;
    const float d3 = el3 - r3;

    int k0 = 0, k1 = 0, k2 = 0, k3 = 0;
    if (d0 < d1) k0++; else k1++;
    if (d0 < d2) k0++; else k2++;
    if (d0 < d3) k0++; else k3++;
    if (d1 < d2) k1++; else k2++;
    if (d1 < d3) k1++; else k3++;
    if (d2 < d3) k2++; else k3++;

    const int s = (int)rintf((((r0 + r1) + r2) + r3) * 0.25f);
    k0 += s; k1 += s; k2 += s; k3 += s;

    if (k0 < 0) { k0 += 4; r0 += 4.0f; } else if (k0 > 3) { k0 -= 4; r0 -= 4.0f; }
    if (k1 < 0) { k1 += 4; r1 += 4.0f; } else if (k1 > 3) { k1 -= 4; r1 -= 4.0f; }
    if (k2 < 0) { k2 += 4; r2 += 4.0f; } else if (k2 > 3) { k2 -= 4; r2 -= 4.0f; }
    if (k3 < 0) { k3 += 4; r3 += 4.0f; } else if (k3 > 3) { k3 -= 4; r3 -= 4.0f; }

    const float dl0 = (el0 - r0) * 0.25f;
    const float dl1 = (el1 - r1) * 0.25f;
    const float dl2 = (el2 - r2) * 0.25f;
    const float dl3 = (el3 - r3) * 0.25f;

    // g[r] = delta of the coord whose rank == r
    const float g0 = (k0 == 0 ? dl0 : 0.0f) + (k1 == 0 ? dl1 : 0.0f) + (k2 == 0 ? dl2 : 0.0f) + (k3 == 0 ? dl3 : 0.0f);
    const float g1 = (k0 == 1 ? dl0 : 0.0f) + (k1 == 1 ? dl1 : 0.0f) + (k2 == 1 ? dl2 : 0.0f) + (k3 == 1 ? dl3 : 0.0f);
    const float g2 = (k0 == 2 ? dl0 : 0.0f) + (k1 == 2 ? dl1 : 0.0f) + (k2 == 2 ? dl2 : 0.0f) + (k3 == 2 ? dl3 : 0.0f);
    const float g3 = (k0 == 3 ? dl0 : 0.0f) + (k1 == 3 ? dl1 : 0.0f) + (k2 == 3 ? dl2 : 0.0f) + (k3 == 3 ? dl3 : 0.0f);

    Prep out;
    out.w0 = g3 + 1.0f - g0;
    out.w1 = g2 - g3;
    out.w2 = g1 - g2;
    out.w3 = g0 - g1;

    const int i0 = (int)r0;
    const int i1 = (int)r1;
    const int i2 = (int)r2;

    unsigned idx[4];
#pragma unroll
    for (int r = 0; r < 4; ++r) {
        const int key0 = i0 + r - ((k0 > 3 - r) ? 4 : 0);
        const int key1 = i1 + r - ((k1 > 3 - r) ? 4 : 0);
        const int key2 = i2 + r - ((k2 > 3 - r) ? 4 : 0);
        const unsigned hsh = (unsigned)key0 * 2654435761u
                           ^ (unsigned)key1 * 805459861u
                           ^ (unsigned)key2 * 3674653429u;
        idx[r] = hsh & CAP_MASK;
    }
    out.i0 = idx[0]; out.i1 = idx[1]; out.i2 = idx[2]; out.i3 = idx[3];
    return out;
}

// Pass 1: level-major gather, XCD affinity (blockIdx&7 -> levels {k,8+k,16+k}),
// 4 points per thread: 16 gathers issued in one batch for 4x MLP per wave.
__global__ __launch_bounds__(256)
void permuto_gather4(const float* __restrict__ pos,
                     const float* __restrict__ lattice,
                     const float* __restrict__ rshift,
                     const float* __restrict__ anneal,
                     float2* __restrict__ ws,
                     ScaleArg sc, int npts, int chunksPerLevel)
{
#pragma clang fp contract(off)
    const int i = blockIdx.x;
    const int xcd = i & 7;
    const int j = i >> 3;
    const int phase = j / chunksPerLevel;        // 0..2
    const int chunk = j - phase * chunksPerLevel;
    const int level = phase * 8 + xcd;           // one coarse/mid/fine per XCD

    const int base = chunk * 1024 + threadIdx.x * 4;
    if (base >= npts) return;

    const float scale = sc.s[level];
    const float s0 = rshift[level * 3 + 0];      // wave-uniform -> scalar loads
    const float s1 = rshift[level * 3 + 1];
    const float s2 = rshift[level * 3 + 2];
    const float a  = anneal[level];

    const float2* __restrict__ tab = (const float2*)lattice + (size_t)level * CAPACITY;
    float2* __restrict__ wrow = ws + (size_t)level * npts;

    if (base + 3 < npts) {
        // 4 consecutive points: 12 floats = 3 dense float4 loads
        const float4* pv = (const float4*)(pos + (size_t)base * 3);
        const float4 f0 = pv[0];
        const float4 f1 = pv[1];
        const float4 f2 = pv[2];
        const float px[4] = { f0.x, f0.w, f1.z, f2.y };
        const float py[4] = { f0.y, f1.x, f1.w, f2.z };
        const float pz[4] = { f0.z, f1.y, f2.x, f2.w };

        Prep pr[4];
#pragma unroll
        for (int k = 0; k < 4; ++k)
            pr[k] = permuto_prep(px[k], py[k], pz[k], scale, s0, s1, s2);

        // batched: all 16 gathers in flight before first use
        float2 v[4][4];
#pragma unroll
        for (int k = 0; k < 4; ++k) {
            v[k][0] = tab[pr[k].i0];
            v[k][1] = tab[pr[k].i1];
            v[k][2] = tab[pr[k].i2];
            v[k][3] = tab[pr[k].i3];
        }

        float2 acc[4];
#pragma unroll
        for (int k = 0; k < 4; ++k) {
            float ax = pr[k].w0 * v[k][0].x + pr[k].w1 * v[k][1].x
                     + pr[k].w2 * v[k][2].x + pr[k].w3 * v[k][3].x;
            float ay = pr[k].w0 * v[k][0].y + pr[k].w1 * v[k][1].y
                     + pr[k].w2 * v[k][2].y + pr[k].w3 * v[k][3].y;
            acc[k] = make_float2(ax * a, ay * a);
        }

        float4* o = (float4*)(wrow + base);
        o[0] = make_float4(acc[0].x, acc[0].y, acc[1].x, acc[1].y);
        o[1] = make_float4(acc[2].x, acc[2].y, acc[3].x, acc[3].y);
    } else {
        // tail: per-point scalar path
        for (int k = 0; k < 4 && base + k < npts; ++k) {
            const int n = base + k;
            Prep pr = permuto_prep(pos[n * 3 + 0], pos[n * 3 + 1], pos[n * 3 + 2],
                                   scale, s0, s1, s2);
            float2 v0 = tab[pr.i0], v1 = tab[pr.i1], v2 = tab[pr.i2], v3 = tab[pr.i3];
            float ax = pr.w0 * v0.x + pr.w1 * v1.x + pr.w2 * v2.x + pr.w3 * v3.x;
            float ay = pr.w0 * v0.y + pr.w1 * v1.y + pr.w2 * v2.y + pr.w3 * v3.y;
            wrow[n] = make_float2(ax * a, ay * a);
        }
    }
}

// Pass 2: (L,N,2) -> (N,L,2) via LDS tile; global writes fully dense per instr.
__global__ __launch_bounds__(256)
void permuto_transpose(const float2* __restrict__ ws,
                       float4* __restrict__ out, int npts)
{
    __shared__ float2 sh[N_LEVELS][257];   // +1 pad: phase-A writes 2-way (free)
    const int t = threadIdx.x;
    const int pbase = blockIdx.x * 256;
    const int valid = npts - pbase;

    if (valid >= 256) {
#pragma unroll
        for (int l = 0; l < N_LEVELS; ++l)
            sh[l][t] = ws[(size_t)l * npts + pbase + t];   // dense 8B/lane reads
        __syncthreads();

        float4* o = out + (size_t)pbase * 12;
#pragma unroll
        for (int s = 0; s < 12; ++s) {
            const int q = s * 256 + t;     // float4 index within block tile
            const int p = q / 12;          // local point
            const int j = q - p * 12;      // float4-within-point = levels 2j,2j+1
            const float2 va = sh[2 * j][p];
            const float2 vb = sh[2 * j + 1][p];
            o[q] = make_float4(va.x, va.y, vb.x, vb.y);    // dense 16B/lane
        }
    } else {
        if (t < valid) {
            const int n = pbase + t;
            float4* o = out + (size_t)n * 12;
#pragma unroll
            for (int j = 0; j < 12; ++j) {
                const float2 va = ws[(size_t)(2 * j) * npts + n];
                const float2 vb = ws[(size_t)(2 * j + 1) * npts + n];
                o[j] = make_float4(va.x, va.y, vb.x, vb.y);
            }
        }
    }
}

// Fallback (ws too small): monolithic, one thread per point.
__global__ __launch_bounds__(256)
void permuto_mono(const float* __restrict__ pos,
                  const float* __restrict__ lattice,
                  const float* __restrict__ rshift,
                  const float* __restrict__ anneal,
                  float* __restrict__ out,
                  ScaleArg sc, int npts)
{
#pragma clang fp contract(off)
    __shared__ float sh_shift[N_LEVELS][3];
    __shared__ float sh_ann[N_LEVELS];
    const int tid = threadIdx.x;
    if (tid < N_LEVELS) {
        sh_shift[tid][0] = rshift[tid * 3 + 0];
        sh_shift[tid][1] = rshift[tid * 3 + 1];
        sh_shift[tid][2] = rshift[tid * 3 + 2];
        sh_ann[tid] = anneal[tid];
    }
    __syncthreads();

    const int n = blockIdx.x * 256 + tid;
    if (n >= npts) return;
    const float p0 = pos[n * 3 + 0];
    const float p1 = pos[n * 3 + 1];
    const float p2 = pos[n * 3 + 2];
    float2* outv = (float2*)out + (size_t)n * N_LEVELS;
    for (int l = 0; l < N_LEVELS; ++l) {
        const float2* tab = (const float2*)lattice + (size_t)l * CAPACITY;
        Prep pr = permuto_prep(p0, p1, p2, sc.s[l],
                               sh_shift[l][0], sh_shift[l][1], sh_shift[l][2]);
        float2 v0 = tab[pr.i0], v1 = tab[pr.i1], v2 = tab[pr.i2], v3 = tab[pr.i3];
        float ax = pr.w0 * v0.x + pr.w1 * v1.x + pr.w2 * v2.x + pr.w3 * v3.x;
        float ay = pr.w0 * v0.y + pr.w1 * v1.y + pr.w2 * v2.y + pr.w3 * v3.y;
        outv[l] = make_float2(ax * sh_ann[l], ay * sh_ann[l]);
    }
}

extern "C" void kernel_launch(void* const* d_in, const int* in_sizes, int n_in,
                              void* d_out, int out_size, void* d_ws, size_t ws_size,
                              hipStream_t stream) {
    const float* pos     = (const float*)d_in[0];
    const float* lattice = (const float*)d_in[1];
    const float* rshift  = (const float*)d_in[2];
    const float* anneal  = (const float*)d_in[3];
    const int npts = in_sizes[0] / 3;

    // np.geomspace(1.0, 1e-4, 24).astype(f32): 10**(i * (-4/23)), endpoints pinned
    ScaleArg sc;
    for (int i = 0; i < N_LEVELS; ++i)
        sc.s[i] = (float)pow(10.0, (double)i * (-4.0 / 23.0));
    sc.s[0] = 1.0f;
    sc.s[N_LEVELS - 1] = 1e-4f;

    const size_t ws_need = (size_t)N_LEVELS * (size_t)npts * sizeof(float2);
    if (ws_size >= ws_need) {
        const int C = (npts + 1023) / 1024;        // 1024-point chunks per level
        const int blocks1 = 8 * 3 * C;             // 24 * C, xcd-swizzled
        permuto_gather4<<<blocks1, 256, 0, stream>>>(
            pos, lattice, rshift, anneal, (float2*)d_ws, sc, npts, C);
        const int blocks2 = (npts + 255) / 256;
        permuto_transpose<<<blocks2, 256, 0, stream>>>(
            (const float2*)d_ws, (float4*)d_out, npts);
    } else {
        const int blocks = (npts + 255) / 256;
        permuto_mono<<<blocks, 256, 0, stream>>>(
            pos, lattice, rshift, anneal, (float*)d_out, sc, npts);
    }
}